// Round 8
// baseline (356.873 us; speedup 1.0000x reference)
//
#include <hip/hip_runtime.h>
#include <stdint.h>

typedef __bf16 bf16;
typedef __bf16 bf16x2 __attribute__((ext_vector_type(2)));
typedef __bf16 bf16x4 __attribute__((ext_vector_type(4)));
typedef __bf16 bf16x8 __attribute__((ext_vector_type(8)));
typedef float f32x4 __attribute__((ext_vector_type(4)));
typedef float f32x16 __attribute__((ext_vector_type(16)));
typedef uint32_t u32;

#define QSCALE 0.1803368801111137f   /* 0.125 * log2(e) */

__device__ __forceinline__ float fast_exp2(float x) {
#if __has_builtin(__builtin_amdgcn_exp2f)
  return __builtin_amdgcn_exp2f(x);
#else
  return exp2f(x);
#endif
}

__device__ __forceinline__ u32 pack_bf16(float a, float b) {
  bf16x2 v; v[0] = (bf16)a; v[1] = (bf16)b;
  return __builtin_bit_cast(u32, v);
}

// async global->LDS, 16B per lane; LDS dest = wave-uniform base + lane*16
__device__ __forceinline__ void async16(void* lds, const void* g) {
  __builtin_amdgcn_global_load_lds(
      (__attribute__((address_space(1))) uint32_t*)(uintptr_t)g,
      (__attribute__((address_space(3))) uint32_t*)(uint32_t)(uintptr_t)lds,
      16, 0, 0);
}

// ---------------- weight conversion (tiled transposes) ----------------
// W{q,k,v}[12][768][64] f32 -> out[2304][768] bf16; out[part*768+h*64+e][d]
__global__ __launch_bounds__(256) void conv_qkv_w_kernel(
    const float* __restrict__ Wq, const float* __restrict__ Wk,
    const float* __restrict__ Wv, bf16* __restrict__ out)
{
  __shared__ float tile[32][33];
  int z = blockIdx.z;              // part*12 + h
  int part = z / 12, h = z - part * 12;
  const float* W = (part == 0) ? Wq : (part == 1) ? Wk : Wv;
  float sc = (part == 0) ? QSCALE : 1.0f;
  int bd = blockIdx.x * 32, be = blockIdx.y * 32;
  int tc = threadIdx.x & 31, tr = threadIdx.x >> 5;
  #pragma unroll
  for (int i = 0; i < 4; i++)
    tile[tr + i * 8][tc] = W[((size_t)h * 768 + bd + tr + i * 8) * 64 + be + tc] * sc;
  __syncthreads();
  #pragma unroll
  for (int i = 0; i < 4; i++) {
    int e = be + tr + i * 8;
    out[(size_t)(part * 768 + h * 64 + e) * 768 + bd + tc] = (bf16)tile[tc][tr + i * 8];
  }
}

__global__ __launch_bounds__(256) void conv_qkv_b_kernel(
    const float* __restrict__ bq, const float* __restrict__ bk,
    const float* __restrict__ bv, float* __restrict__ out)
{
  int n = blockIdx.x * 256 + threadIdx.x;  // 2304
  int part = n / 768, nn = n - part * 768;
  const float* B = (part == 0) ? bq : (part == 1) ? bk : bv;
  float v = B[nn];
  if (part == 0) v *= QSCALE;
  out[n] = v;
}

// f32 in[R][C] -> bf16 out[C][R], grid (C/32, R/32)
__global__ __launch_bounds__(256) void transpose_tile_kernel(
    const float* __restrict__ in, bf16* __restrict__ out, int R, int C)
{
  __shared__ float tile[32][33];
  int bc = blockIdx.x * 32, br = blockIdx.y * 32;
  int tc = threadIdx.x & 31, tr = threadIdx.x >> 5;
  #pragma unroll
  for (int i = 0; i < 4; i++)
    tile[tr + i * 8][tc] = in[(size_t)(br + tr + i * 8) * C + bc + tc];
  __syncthreads();
  #pragma unroll
  for (int i = 0; i < 4; i++) {
    int c = bc + tr + i * 8;
    out[(size_t)c * R + br + tc] = (bf16)tile[tc][tr + i * 8];
  }
}

// out[i] += (float)p[i], float4/bf16x4-wide; grid 3072 x 256 over 4096*768
__global__ __launch_bounds__(256) void reduce_add_kernel(
    float* __restrict__ out, const bf16* __restrict__ p)
{
  int i = blockIdx.x * 256 + threadIdx.x;
  float4 o = ((float4*)out)[i];
  bf16x4 v = ((const bf16x4*)p)[i];
  o.x += (float)v[0]; o.y += (float)v[1];
  o.z += (float)v[2]; o.w += (float)v[3];
  ((float4*)out)[i] = o;
}

// ---------------- layernorm (fp32 in, bf16 out) ----------------
__global__ __launch_bounds__(256) void ln_kernel(
    const float* __restrict__ x, const float* __restrict__ w,
    const float* __restrict__ b, bf16* __restrict__ y)
{
  int row = blockIdx.x;
  const float* xr = x + (size_t)row * 768;
  int t = threadIdx.x;
  float v0 = xr[t], v1 = xr[t + 256], v2 = xr[t + 512];
  float s = v0 + v1 + v2, s2 = v0 * v0 + v1 * v1 + v2 * v2;
  #pragma unroll
  for (int d = 1; d < 64; d <<= 1) {
    s  += __shfl_xor(s, d, 64);
    s2 += __shfl_xor(s2, d, 64);
  }
  __shared__ float red[8];
  int wv = t >> 6, ln = t & 63;
  if (ln == 0) { red[wv] = s; red[4 + wv] = s2; }
  __syncthreads();
  s  = red[0] + red[1] + red[2] + red[3];
  s2 = red[4] + red[5] + red[6] + red[7];
  float mu = s * (1.0f / 768.0f);
  float var = s2 * (1.0f / 768.0f) - mu * mu;
  float rstd = rsqrtf(var + 1e-5f);
  bf16* yr = y + (size_t)row * 768;
  yr[t]       = (bf16)((v0 - mu) * rstd * w[t]       + b[t]);
  yr[t + 256] = (bf16)((v1 - mu) * rstd * w[t + 256] + b[t + 256]);
  yr[t + 512] = (bf16)((v2 - mu) * rstd * w[t + 512] + b[t + 512]);
}

// ---------------- GEMM: C = A[M][K] * Bt[N][K]^T, m97 structure ----------------
// MODE 2: out bf16 = gelu(acc + bias)   (exact erf)
// MODE 4: QKV split: col<1536 -> qk[row][col]; else V^T: out2[(col-1536)*4096+row]
// MODE 5: split-K x2 (gridDim.z=2): z=0 -> f32 outp = res+acc+bias;
//         z=1 -> bf16 partial out2 = acc (reduced by reduce_add_kernel)
template <int MODE>
__global__ __launch_bounds__(256) void gemm_bt(
    const bf16* __restrict__ A, const bf16* __restrict__ Bt,
    const float* __restrict__ bias, const float* __restrict__ res,
    void* __restrict__ outp, void* __restrict__ out2, int M, int N, int K)
{
  __shared__ bf16 As[128 * 32];
  __shared__ bf16 Bs[128 * 32];
  int t = threadIdx.x;
  int w = t >> 6, lane = t & 63;
  int quad = lane >> 4, l16 = lane & 15;
  int tile_m = blockIdx.y * 128, tile_n = blockIdx.x * 128;

  int srow = lane >> 2;
  int skb = (lane & 3) * 8;
  const bf16* Ag = A  + (size_t)(tile_m + w * 16 + srow) * K + skb;
  const bf16* Bg = Bt + (size_t)(tile_n + w * 16 + srow) * K + skb;
  char* AsB = (char*)As + w * 1024;
  char* BsB = (char*)Bs + w * 1024;
  size_t rstep = (size_t)64 * K;

  int wm = (w >> 1) * 64, wn = (w & 1) * 64;
  f32x4 acc[4][4] = {};

  int kbeg = 0, kend = K;
  if (MODE == 5) {
    int half = K >> 1;
    kbeg = blockIdx.z * half;
    kend = kbeg + half;
  }

  for (int k0 = kbeg; k0 < kend; k0 += 32) {
    __syncthreads();
    async16(AsB,        Ag + k0);
    async16(AsB + 4096, Ag + rstep + k0);
    async16(BsB,        Bg + k0);
    async16(BsB + 4096, Bg + rstep + k0);
    __syncthreads();

    bf16x8 af[4], bfr[4];
    #pragma unroll
    for (int mb = 0; mb < 4; mb++)
      af[mb] = *(const bf16x8*)(As + (wm + mb * 16 + l16) * 32 + quad * 8);
    #pragma unroll
    for (int nb = 0; nb < 4; nb++)
      bfr[nb] = *(const bf16x8*)(Bs + (wn + nb * 16 + l16) * 32 + quad * 8);
    #pragma unroll
    for (int mb = 0; mb < 4; mb++)
      #pragma unroll
      for (int nb = 0; nb < 4; nb++)
        acc[mb][nb] = __builtin_amdgcn_mfma_f32_16x16x32_bf16(
            af[mb], bfr[nb], acc[mb][nb], 0, 0, 0);
  }

  #pragma unroll
  for (int mb = 0; mb < 4; mb++) {
    #pragma unroll
    for (int nb = 0; nb < 4; nb++) {
      int col = tile_n + wn + nb * 16 + l16;
      int row0 = tile_m + wm + mb * 16 + quad * 4;
      if (MODE == 4) {
        float bc = bias[col];
        if (col < 1536) {
          #pragma unroll
          for (int r = 0; r < 4; r++)
            ((bf16*)outp)[(size_t)(row0 + r) * 1536 + col] =
                (bf16)(acc[mb][nb][r] + bc);
        } else {
          bf16x4 pk;
          #pragma unroll
          for (int r = 0; r < 4; r++) pk[r] = (bf16)(acc[mb][nb][r] + bc);
          *(bf16x4*)((bf16*)out2 + (size_t)(col - 1536) * 4096 + row0) = pk;
        }
      } else if (MODE == 2) {
        float bc = bias[col];
        #pragma unroll
        for (int r = 0; r < 4; r++) {
          size_t idx = (size_t)(row0 + r) * N + col;
          float v = acc[mb][nb][r] + bc;
          float g = 0.5f * v * (1.0f + erff(v * 0.70710678118654752f));
          ((bf16*)outp)[idx] = (bf16)g;
        }
      } else {  // MODE 5
        if (blockIdx.z == 0) {
          float bc = bias[col];
          #pragma unroll
          for (int r = 0; r < 4; r++) {
            size_t idx = (size_t)(row0 + r) * N + col;
            ((float*)outp)[idx] = res[idx] + acc[mb][nb][r] + bc;
          }
        } else {
          #pragma unroll
          for (int r = 0; r < 4; r++) {
            size_t idx = (size_t)(row0 + r) * N + col;
            ((bf16*)out2)[idx] = (bf16)acc[mb][nb][r];
          }
        }
      }
    }
  }
}

// ---------------- flash attention v5 ----------------
// Single-barrier K-loop with double-buffered K/V staging: loads for tile j+1
// are issued BEFORE computing tile j, so their latency is hidden under the
// full tile-j compute; the one barrier (end of iter) drains them.
// 32x32x16 MFMA, 2x2 wave tiling, no-max exp2 softmax, NO kv-split
// (full 4096-kv loop per block; direct normalized output, no combine pass).
// grid (64 qtile, 12 head); block 256 = 4 waves; LDS 40KB -> 3 blocks/CU exact.
// qk:  [4096][1536] bf16 (Q pre-scaled by 0.125*log2e | K), cols h*64+e
// vtg: [768][4096]  bf16 = V^T: row h*64+e, col s
__global__ __launch_bounds__(256) void flash_kernel(
    const bf16* __restrict__ qk, const bf16* __restrict__ vtg,
    bf16* __restrict__ o)
{
  __shared__ char smem[40960];
  bf16* Qs = (bf16*)smem;                        // [64][64] 8KB
  // K buffers at 8192 + cur*8192; V buffers at 24576 + cur*8192
  int t = threadIdx.x, w = t >> 6, lane = t & 63;
  int l32 = lane & 31, hi = lane >> 5;
  int qt = blockIdx.x, h = blockIdx.y;
  int q0 = qt * 64;
  int qsel = w & 1, ksel = w >> 1;
  int qb = qsel * 32, kb = ksel * 32;

  int srow = lane >> 3, scol = ((lane & 7) ^ srow) * 8;

  { // stage Q once
    const bf16* qg = qk + (size_t)(q0 + w * 8 + srow) * 1536 + h * 64 + scol;
    char* base = smem + w * 1024;
    async16(base,        qg);
    async16(base + 4096, qg + (size_t)32 * 1536);
  }

  const bf16* kg = qk + 768 + h * 64 + (size_t)(w * 8 + srow) * 1536 + scol;
  const bf16* vg = vtg + (size_t)(h * 64 + w * 8 + srow) * 4096 + scol;

  { // stage K/V tile 0 into buffer 0
    char* kb0 = smem + 8192  + w * 1024;
    char* vb0 = smem + 24576 + w * 1024;
    async16(kb0,        kg);
    async16(kb0 + 4096, kg + (size_t)32 * 1536);
    async16(vb0,        vg);
    async16(vb0 + 4096, vg + (size_t)32 * 4096);
  }
  __syncthreads();   // Q + tile 0 resident

  // hoist Q fragments: B[n=q=qb+l32][k=ks*16+hi*8+j]
  int qrow = qb + l32;
  bf16x8 qf[4];
  #pragma unroll
  for (int ks = 0; ks < 4; ks++) {
    int pos = (ks * 2 + hi) ^ (qrow & 7);
    qf[ks] = *(const bf16x8*)(Qs + qrow * 64 + pos * 8);
  }

  f32x16 oT0 = {}, oT1 = {};
  float l_lane = 0.0f;
  int krow = kb + l32;
  int erow0 = l32, erow1 = 32 + l32;

  for (int j = 0; j < 64; j++) {
    int cur = j & 1;
    if (j < 63) {   // prefetch tile j+1 into the other buffer (overlaps compute)
      const bf16* kgn = kg + (size_t)(j + 1) * 64 * 1536;
      const bf16* vgn = vg + (j + 1) * 64;
      char* kbn = smem + 8192  + (cur ^ 1) * 8192 + w * 1024;
      char* vbn = smem + 24576 + (cur ^ 1) * 8192 + w * 1024;
      async16(kbn,        kgn);
      async16(kbn + 4096, kgn + (size_t)32 * 1536);
      async16(vbn,        vgn);
      async16(vbn + 4096, vgn + (size_t)32 * 4096);
    }
    const bf16* Ks = (const bf16*)(smem + 8192  + cur * 8192);
    const bf16* Vs = (const bf16*)(smem + 24576 + cur * 8192);

    // S^T = K Q^T over hd=64: 4 MFMAs 32x32x16
    f32x16 sT = {};
    #pragma unroll
    for (int ks = 0; ks < 4; ks++) {
      int pos = (ks * 2 + hi) ^ (krow & 7);
      bf16x8 kf = *(const bf16x8*)(Ks + krow * 64 + pos * 8);
      sT = __builtin_amdgcn_mfma_f32_32x32x16_bf16(kf, qf[ks], sT, 0, 0, 0);
    }

    // no-max softmax: p = exp2(s); lane holds 16 kv values of one q column
    float rs = 0.0f;
    #pragma unroll
    for (int i = 0; i < 16; i++) {
      float p = fast_exp2(sT[i]);
      sT[i] = p;
      rs += p;
    }
    l_lane += rs;

    // P^T B-fragments in-register: pack bf16 pairs, exchange with lane^32.
    // sT reg i holds P^T[kv_local=(i&3)+8*(i>>2)+4*hi][q=qb+l32].
    u32 dd[8], xx[8];
    #pragma unroll
    for (int k = 0; k < 8; k++) dd[k] = pack_bf16(sT[2 * k], sT[2 * k + 1]);
    #pragma unroll
    for (int k = 0; k < 8; k++) xx[k] = __shfl_xor((int)dd[k], 32, 64);
    uint4 p0 = hi ? uint4{xx[2], xx[3], dd[2], dd[3]}
                  : uint4{dd[0], dd[1], xx[0], xx[1]};
    uint4 p1 = hi ? uint4{xx[6], xx[7], dd[6], dd[7]}
                  : uint4{dd[4], dd[5], xx[4], xx[5]};
    bf16x8 pf0 = __builtin_bit_cast(bf16x8, p0);   // kv kb+0..15
    bf16x8 pf1 = __builtin_bit_cast(bf16x8, p1);   // kv kb+16..31

    // O^T += V^T P^T over this wave's kv 32
    #pragma unroll
    for (int ks = 0; ks < 2; ks++) {
      int grp = (kb >> 3) + ks * 2 + hi;
      bf16x8 pf  = ks ? pf1 : pf0;
      bf16x8 vf0 = *(const bf16x8*)(Vs + erow0 * 64 + (grp ^ (erow0 & 7)) * 8);
      bf16x8 vf1 = *(const bf16x8*)(Vs + erow1 * 64 + (grp ^ (erow1 & 7)) * 8);
      oT0 = __builtin_amdgcn_mfma_f32_32x32x16_bf16(vf0, pf, oT0, 0, 0, 0);
      oT1 = __builtin_amdgcn_mfma_f32_32x32x16_bf16(vf1, pf, oT1, 0, 0, 0);
    }

    __syncthreads();   // drains j+1 loads (hidden under compute) + guards buf reuse
  }

  // combine the two ksel halves within the block via LDS (OS stride 68)
  float l_q = l_lane + __shfl_xor(l_lane, 32, 64);   // lanes l, l^32 share q col
  float* OS = (float*)smem;            // [64 q][68] f32 (17408 B)
  float* LS = (float*)(smem + 17408);  // [64 q] f32
  if (ksel == 1) {
    #pragma unroll
    for (int i = 0; i < 16; i++) {
      int e0 = (i & 3) + 8 * (i >> 2) + 4 * hi;
      OS[qrow * 68 + e0]      = oT0[i];
      OS[qrow * 68 + 32 + e0] = oT1[i];
    }
    if (hi == 0) LS[qrow] = l_q;
  }
  __syncthreads();
  if (ksel == 0) {
    float inv = 1.0f / (l_q + LS[qrow]);
    bf16* ob = o + (size_t)(q0 + qrow) * 768 + h * 64;
    #pragma unroll
    for (int g = 0; g < 4; g++) {
      int e0 = 8 * g + 4 * hi;
      bf16x4 pk0, pk1;
      #pragma unroll
      for (int r = 0; r < 4; r++) {
        pk0[r] = (bf16)((oT0[g * 4 + r] + OS[qrow * 68 + e0 + r]) * inv);
        pk1[r] = (bf16)((oT1[g * 4 + r] + OS[qrow * 68 + 32 + e0 + r]) * inv);
      }
      *(bf16x4*)(ob + e0)      = pk0;
      *(bf16x4*)(ob + 32 + e0) = pk1;
    }
  }
}

extern "C" void kernel_launch(void* const* d_in, const int* in_sizes, int n_in,
                              void* d_out, int out_size, void* d_ws, size_t ws_size,
                              hipStream_t stream) {
  const float* x    = (const float*)d_in[0];
  const float* Wq   = (const float*)d_in[1];
  const float* bq   = (const float*)d_in[2];
  const float* Wk   = (const float*)d_in[3];
  const float* bk   = (const float*)d_in[4];
  const float* Wv   = (const float*)d_in[5];
  const float* bv   = (const float*)d_in[6];
  const float* Wo   = (const float*)d_in[7];
  const float* bo   = (const float*)d_in[8];
  const float* ln1w = (const float*)d_in[9];
  const float* ln1b = (const float*)d_in[10];
  const float* ln2w = (const float*)d_in[11];
  const float* ln2b = (const float*)d_in[12];
  const float* W1   = (const float*)d_in[13];
  const float* b1   = (const float*)d_in[14];
  const float* W2   = (const float*)d_in[15];
  const float* b2   = (const float*)d_in[16];
  float* out = (float*)d_out;

  // workspace layout (58,205,184 B):
  //  0         .. 25165824 : hbuf [4096][3072] bf16 (FFN1 out)
  //                          earlier: ybuf(0..6291456, ln1)
  //                          qkbuf(6291456..18874368) / vtg(18874368..25165824)
  //                          opar_o(6291456..12582912, O-proj z=1 partial)
  //  25165824  .. 37748736 : x1 f32 [4096][768]
  //  37748736  .. 44040192 : obuf/y2buf bf16 [4096][768]; later FFN2 z=1 partial
  //  44040192  .. 58195968 : Wqkv_t | Wo_t | W1_t | W2_t (bf16)
  //  58195968  .. 58205184 : bqkv f32 [2304]
  char* ws = (char*)d_ws;
  bf16*  hbuf   = (bf16*)(ws + 0);
  bf16*  ybuf   = (bf16*)(ws + 0);
  bf16*  qkbuf  = (bf16*)(ws + 6291456);
  bf16*  opar_o = (bf16*)(ws + 6291456);
  bf16*  vtg    = (bf16*)(ws + 18874368);
  float* x1     = (float*)(ws + 25165824);
  bf16*  obuf   = (bf16*)(ws + 37748736);
  bf16*  y2buf  = obuf;
  bf16*  opar_f = obuf;                      // FFN2 z=1 partial (y2 dead)
  bf16*  Wqkv_t = (bf16*)(ws + 44040192);
  bf16*  Wo_t   = (bf16*)(ws + 47579136);
  bf16*  W1_t   = (bf16*)(ws + 48758784);
  bf16*  W2_t   = (bf16*)(ws + 53477376);
  float* bqkv   = (float*)(ws + 58195968);

  // weight prep (ws re-poisoned every call -> reconvert every call)
  conv_qkv_w_kernel<<<dim3(24, 2, 36), 256, 0, stream>>>(Wq, Wk, Wv, Wqkv_t);
  conv_qkv_b_kernel<<<9, 256, 0, stream>>>(bq, bk, bv, bqkv);
  transpose_tile_kernel<<<dim3(24, 24), 256, 0, stream>>>(Wo, Wo_t, 768, 768);
  transpose_tile_kernel<<<dim3(96, 24), 256, 0, stream>>>(W1, W1_t, 768, 3072);
  transpose_tile_kernel<<<dim3(24, 96), 256, 0, stream>>>(W2, W2_t, 3072, 768);

  // 1) y = LN1(x)
  ln_kernel<<<4096, 256, 0, stream>>>(x, ln1w, ln1b, ybuf);
  // 2) qk | v^T = y @ Wqkv + bqkv   (Q pre-scaled by 0.125*log2e)
  gemm_bt<4><<<dim3(18, 32), 256, 0, stream>>>(ybuf, Wqkv_t, bqkv,
                                               (const float*)nullptr, qkbuf, vtg,
                                               4096, 2304, 768);
  // 3) flash attention -> obuf [4096][768] (direct, normalized)
  flash_kernel<<<dim3(64, 12), 256, 0, stream>>>(qkbuf, vtg, obuf);
  // 4) x1 = x + obuf @ Wo + bo  (split-K x2, bf16 partial + reduce)
  gemm_bt<5><<<dim3(6, 32, 2), 256, 0, stream>>>(obuf, Wo_t, bo, x, x1, opar_o,
                                                 4096, 768, 768);
  reduce_add_kernel<<<3072, 256, 0, stream>>>(x1, opar_o);
  // 5) y2 = LN2(x1)
  ln_kernel<<<4096, 256, 0, stream>>>(x1, ln2w, ln2b, y2buf);
  // 6) h = gelu(y2 @ W1 + b1)
  gemm_bt<2><<<dim3(24, 32), 256, 0, stream>>>(y2buf, W1_t, b1,
                                               (const float*)nullptr, hbuf, nullptr,
                                               4096, 3072, 768);
  // 7) out = x1 + h @ W2 + b2  (split-K x2, bf16 partial + reduce)
  gemm_bt<5><<<dim3(6, 32, 2), 256, 0, stream>>>(hbuf, W2_t, b2, x1, out, opar_f,
                                                 4096, 768, 3072);
  reduce_add_kernel<<<3072, 256, 0, stream>>>(out, opar_f);
}

// Round 9
// 355.001 us; speedup vs baseline: 1.0053x; 1.0053x over previous
//
#include <hip/hip_runtime.h>
#include <stdint.h>

typedef __bf16 bf16;
typedef __bf16 bf16x2 __attribute__((ext_vector_type(2)));
typedef __bf16 bf16x4 __attribute__((ext_vector_type(4)));
typedef __bf16 bf16x8 __attribute__((ext_vector_type(8)));
typedef float f32x4 __attribute__((ext_vector_type(4)));
typedef float f32x16 __attribute__((ext_vector_type(16)));
typedef uint32_t u32;

#define QSCALE 0.1803368801111137f   /* 0.125 * log2(e) */

__device__ __forceinline__ float fast_exp2(float x) {
#if __has_builtin(__builtin_amdgcn_exp2f)
  return __builtin_amdgcn_exp2f(x);
#else
  return exp2f(x);
#endif
}

__device__ __forceinline__ u32 pack_bf16(float a, float b) {
  bf16x2 v; v[0] = (bf16)a; v[1] = (bf16)b;
  return __builtin_bit_cast(u32, v);
}

// async global->LDS, 16B per lane; LDS dest = wave-uniform base + lane*16
__device__ __forceinline__ void async16(void* lds, const void* g) {
  __builtin_amdgcn_global_load_lds(
      (__attribute__((address_space(1))) uint32_t*)(uintptr_t)g,
      (__attribute__((address_space(3))) uint32_t*)(uint32_t)(uintptr_t)lds,
      16, 0, 0);
}

// ---------------- weight conversion (tiled transposes) ----------------
// W{q,k,v}[12][768][64] f32 -> out[2304][768] bf16; out[part*768+h*64+e][d]
__global__ __launch_bounds__(256) void conv_qkv_w_kernel(
    const float* __restrict__ Wq, const float* __restrict__ Wk,
    const float* __restrict__ Wv, bf16* __restrict__ out)
{
  __shared__ float tile[32][33];
  int z = blockIdx.z;              // part*12 + h
  int part = z / 12, h = z - part * 12;
  const float* W = (part == 0) ? Wq : (part == 1) ? Wk : Wv;
  float sc = (part == 0) ? QSCALE : 1.0f;
  int bd = blockIdx.x * 32, be = blockIdx.y * 32;
  int tc = threadIdx.x & 31, tr = threadIdx.x >> 5;
  #pragma unroll
  for (int i = 0; i < 4; i++)
    tile[tr + i * 8][tc] = W[((size_t)h * 768 + bd + tr + i * 8) * 64 + be + tc] * sc;
  __syncthreads();
  #pragma unroll
  for (int i = 0; i < 4; i++) {
    int e = be + tr + i * 8;
    out[(size_t)(part * 768 + h * 64 + e) * 768 + bd + tc] = (bf16)tile[tc][tr + i * 8];
  }
}

__global__ __launch_bounds__(256) void conv_qkv_b_kernel(
    const float* __restrict__ bq, const float* __restrict__ bk,
    const float* __restrict__ bv, float* __restrict__ out)
{
  int n = blockIdx.x * 256 + threadIdx.x;  // 2304
  int part = n / 768, nn = n - part * 768;
  const float* B = (part == 0) ? bq : (part == 1) ? bk : bv;
  float v = B[nn];
  if (part == 0) v *= QSCALE;
  out[n] = v;
}

// f32 in[R][C] -> bf16 out[C][R], grid (C/32, R/32)
__global__ __launch_bounds__(256) void transpose_tile_kernel(
    const float* __restrict__ in, bf16* __restrict__ out, int R, int C)
{
  __shared__ float tile[32][33];
  int bc = blockIdx.x * 32, br = blockIdx.y * 32;
  int tc = threadIdx.x & 31, tr = threadIdx.x >> 5;
  #pragma unroll
  for (int i = 0; i < 4; i++)
    tile[tr + i * 8][tc] = in[(size_t)(br + tr + i * 8) * C + bc + tc];
  __syncthreads();
  #pragma unroll
  for (int i = 0; i < 4; i++) {
    int c = bc + tr + i * 8;
    out[(size_t)c * R + br + tc] = (bf16)tile[tc][tr + i * 8];
  }
}

// out[i] += (float)p[i], float4/bf16x4-wide; grid 3072 x 256 over 4096*768
__global__ __launch_bounds__(256) void reduce_add_kernel(
    float* __restrict__ out, const bf16* __restrict__ p)
{
  int i = blockIdx.x * 256 + threadIdx.x;
  float4 o = ((float4*)out)[i];
  bf16x4 v = ((const bf16x4*)p)[i];
  o.x += (float)v[0]; o.y += (float)v[1];
  o.z += (float)v[2]; o.w += (float)v[3];
  ((float4*)out)[i] = o;
}

// ---------------- layernorm (fp32 in, bf16 out) ----------------
__global__ __launch_bounds__(256) void ln_kernel(
    const float* __restrict__ x, const float* __restrict__ w,
    const float* __restrict__ b, bf16* __restrict__ y)
{
  int row = blockIdx.x;
  const float* xr = x + (size_t)row * 768;
  int t = threadIdx.x;
  float v0 = xr[t], v1 = xr[t + 256], v2 = xr[t + 512];
  float s = v0 + v1 + v2, s2 = v0 * v0 + v1 * v1 + v2 * v2;
  #pragma unroll
  for (int d = 1; d < 64; d <<= 1) {
    s  += __shfl_xor(s, d, 64);
    s2 += __shfl_xor(s2, d, 64);
  }
  __shared__ float red[8];
  int wv = t >> 6, ln = t & 63;
  if (ln == 0) { red[wv] = s; red[4 + wv] = s2; }
  __syncthreads();
  s  = red[0] + red[1] + red[2] + red[3];
  s2 = red[4] + red[5] + red[6] + red[7];
  float mu = s * (1.0f / 768.0f);
  float var = s2 * (1.0f / 768.0f) - mu * mu;
  float rstd = rsqrtf(var + 1e-5f);
  bf16* yr = y + (size_t)row * 768;
  yr[t]       = (bf16)((v0 - mu) * rstd * w[t]       + b[t]);
  yr[t + 256] = (bf16)((v1 - mu) * rstd * w[t + 256] + b[t + 256]);
  yr[t + 512] = (bf16)((v2 - mu) * rstd * w[t + 512] + b[t + 512]);
}

// fused: x1 += (float)p; y = LN(x1)  — saves a full reduce pass over x1
__global__ __launch_bounds__(256) void ln_add_kernel(
    float* __restrict__ x1, const bf16* __restrict__ p,
    const float* __restrict__ w, const float* __restrict__ b,
    bf16* __restrict__ y)
{
  int row = blockIdx.x;
  float* xr = x1 + (size_t)row * 768;
  const bf16* pr = p + (size_t)row * 768;
  int t = threadIdx.x;
  float v0 = xr[t]       + (float)pr[t];
  float v1 = xr[t + 256] + (float)pr[t + 256];
  float v2 = xr[t + 512] + (float)pr[t + 512];
  xr[t] = v0; xr[t + 256] = v1; xr[t + 512] = v2;
  float s = v0 + v1 + v2, s2 = v0 * v0 + v1 * v1 + v2 * v2;
  #pragma unroll
  for (int d = 1; d < 64; d <<= 1) {
    s  += __shfl_xor(s, d, 64);
    s2 += __shfl_xor(s2, d, 64);
  }
  __shared__ float red[8];
  int wv = t >> 6, ln = t & 63;
  if (ln == 0) { red[wv] = s; red[4 + wv] = s2; }
  __syncthreads();
  s  = red[0] + red[1] + red[2] + red[3];
  s2 = red[4] + red[5] + red[6] + red[7];
  float mu = s * (1.0f / 768.0f);
  float var = s2 * (1.0f / 768.0f) - mu * mu;
  float rstd = rsqrtf(var + 1e-5f);
  bf16* yr = y + (size_t)row * 768;
  yr[t]       = (bf16)((v0 - mu) * rstd * w[t]       + b[t]);
  yr[t + 256] = (bf16)((v1 - mu) * rstd * w[t + 256] + b[t + 256]);
  yr[t + 512] = (bf16)((v2 - mu) * rstd * w[t + 512] + b[t + 512]);
}

// ---------------- GEMM: C = A[M][K] * Bt[N][K]^T, m97 structure ----------------
// MODE 2: out bf16 = gelu(acc + bias)   (exact erf)
// MODE 4: QKV split: col<1536 -> qk[row][col]; else V^T: out2[(col-1536)*4096+row]
// MODE 5: split-K x2 (gridDim.z=2): z=0 -> f32 outp = res+acc+bias;
//         z=1 -> bf16 partial out2 = acc (reduced later)
template <int MODE>
__global__ __launch_bounds__(256) void gemm_bt(
    const bf16* __restrict__ A, const bf16* __restrict__ Bt,
    const float* __restrict__ bias, const float* __restrict__ res,
    void* __restrict__ outp, void* __restrict__ out2, int M, int N, int K)
{
  __shared__ bf16 As[128 * 32];
  __shared__ bf16 Bs[128 * 32];
  int t = threadIdx.x;
  int w = t >> 6, lane = t & 63;
  int quad = lane >> 4, l16 = lane & 15;
  int tile_m = blockIdx.y * 128, tile_n = blockIdx.x * 128;

  int srow = lane >> 2;
  int skb = (lane & 3) * 8;
  const bf16* Ag = A  + (size_t)(tile_m + w * 16 + srow) * K + skb;
  const bf16* Bg = Bt + (size_t)(tile_n + w * 16 + srow) * K + skb;
  char* AsB = (char*)As + w * 1024;
  char* BsB = (char*)Bs + w * 1024;
  size_t rstep = (size_t)64 * K;

  int wm = (w >> 1) * 64, wn = (w & 1) * 64;
  f32x4 acc[4][4] = {};

  int kbeg = 0, kend = K;
  if (MODE == 5) {
    int half = K >> 1;
    kbeg = blockIdx.z * half;
    kend = kbeg + half;
  }

  for (int k0 = kbeg; k0 < kend; k0 += 32) {
    __syncthreads();
    async16(AsB,        Ag + k0);
    async16(AsB + 4096, Ag + rstep + k0);
    async16(BsB,        Bg + k0);
    async16(BsB + 4096, Bg + rstep + k0);
    __syncthreads();

    bf16x8 af[4], bfr[4];
    #pragma unroll
    for (int mb = 0; mb < 4; mb++)
      af[mb] = *(const bf16x8*)(As + (wm + mb * 16 + l16) * 32 + quad * 8);
    #pragma unroll
    for (int nb = 0; nb < 4; nb++)
      bfr[nb] = *(const bf16x8*)(Bs + (wn + nb * 16 + l16) * 32 + quad * 8);
    #pragma unroll
    for (int mb = 0; mb < 4; mb++)
      #pragma unroll
      for (int nb = 0; nb < 4; nb++)
        acc[mb][nb] = __builtin_amdgcn_mfma_f32_16x16x32_bf16(
            af[mb], bfr[nb], acc[mb][nb], 0, 0, 0);
  }

  #pragma unroll
  for (int mb = 0; mb < 4; mb++) {
    #pragma unroll
    for (int nb = 0; nb < 4; nb++) {
      int col = tile_n + wn + nb * 16 + l16;
      int row0 = tile_m + wm + mb * 16 + quad * 4;
      if (MODE == 4) {
        float bc = bias[col];
        if (col < 1536) {
          #pragma unroll
          for (int r = 0; r < 4; r++)
            ((bf16*)outp)[(size_t)(row0 + r) * 1536 + col] =
                (bf16)(acc[mb][nb][r] + bc);
        } else {
          bf16x4 pk;
          #pragma unroll
          for (int r = 0; r < 4; r++) pk[r] = (bf16)(acc[mb][nb][r] + bc);
          *(bf16x4*)((bf16*)out2 + (size_t)(col - 1536) * 4096 + row0) = pk;
        }
      } else if (MODE == 2) {
        float bc = bias[col];
        #pragma unroll
        for (int r = 0; r < 4; r++) {
          size_t idx = (size_t)(row0 + r) * N + col;
          float v = acc[mb][nb][r] + bc;
          float g = 0.5f * v * (1.0f + erff(v * 0.70710678118654752f));
          ((bf16*)outp)[idx] = (bf16)g;
        }
      } else {  // MODE 5
        if (blockIdx.z == 0) {
          float bc = bias[col];
          #pragma unroll
          for (int r = 0; r < 4; r++) {
            size_t idx = (size_t)(row0 + r) * N + col;
            ((float*)outp)[idx] = res[idx] + acc[mb][nb][r] + bc;
          }
        } else {
          #pragma unroll
          for (int r = 0; r < 4; r++) {
            size_t idx = (size_t)(row0 + r) * N + col;
            ((bf16*)out2)[idx] = (bf16)acc[mb][nb][r];
          }
        }
      }
    }
  }
}

// ---------------- flash attention v6 ----------------
// Q=128 per block: doubles compute per staged K/V byte so the dbuf prefetch
// latency is actually covered (v5's Q=64 exposed ~500cyc/iter at the barrier).
// 32x32x16 MFMA; waves 2x2 (qsel: 64-q half, ksel: 32-kv half); each wave does
// 16 MFMA + 32 exp2 per iter; K/V fragments shared across the two q-subtiles.
// kv-split x2 -> grid (32 qt, 12 h, 2 z) = 768 = 3 blocks/CU @ 48KB LDS.
// qk:  [4096][1536] bf16 (Q pre-scaled by 0.125*log2e | K), cols h*64+e
// vtg: [768][4096]  bf16 = V^T: row h*64+e, col s
// Out (unnormalized): Opart[((z*12+h)*32+qt)][128 q][64 e] bf16, Lpart[...][128 q]
__global__ __launch_bounds__(256) void flash_kernel(
    const bf16* __restrict__ qk, const bf16* __restrict__ vtg,
    bf16* __restrict__ Opart, float* __restrict__ Lpart)
{
  __shared__ char smem[49152];
  bf16* Qs = (bf16*)smem;   // [128 q][64 hd] 16KB; K dbuf @16384+cur*8192; V @32768+cur*8192
  int t = threadIdx.x, w = t >> 6, lane = t & 63;
  int l32 = lane & 31, hi = lane >> 5;
  int qt = blockIdx.x, h = blockIdx.y, z = blockIdx.z;
  int q0 = qt * 128, kv0 = z * 2048;
  int qsel = w & 1, ksel = w >> 1;
  int qw = qsel * 64, kb = ksel * 32;

  int srow = lane >> 3, scol = ((lane & 7) ^ srow) * 8;

  // stage Q (4 rounds x 32 rows)
  #pragma unroll
  for (int c = 0; c < 4; c++) {
    const bf16* qg = qk + (size_t)(q0 + c * 32 + w * 8 + srow) * 1536 + h * 64 + scol;
    async16(smem + c * 4096 + w * 1024, qg);
  }

  const bf16* kg = qk + 768 + h * 64 + (size_t)(kv0 + w * 8 + srow) * 1536 + scol;
  const bf16* vg = vtg + (size_t)(h * 64 + w * 8 + srow) * 4096 + kv0 + scol;

  { // K/V tile 0 -> buffer 0
    char* kb0 = smem + 16384 + w * 1024;
    char* vb0 = smem + 32768 + w * 1024;
    async16(kb0,        kg);
    async16(kb0 + 4096, kg + (size_t)32 * 1536);
    async16(vb0,        vg);
    async16(vb0 + 4096, vg + (size_t)32 * 4096);
  }
  __syncthreads();

  // hoist Q fragments for both q-subtiles (B-operand [q][hd])
  int qr0 = qw + l32, qr1 = qw + 32 + l32;
  bf16x8 qf0[4], qf1[4];
  #pragma unroll
  for (int ks = 0; ks < 4; ks++) {
    qf0[ks] = *(const bf16x8*)(Qs + qr0 * 64 + (((ks * 2 + hi) ^ (qr0 & 7)) * 8));
    qf1[ks] = *(const bf16x8*)(Qs + qr1 * 64 + (((ks * 2 + hi) ^ (qr1 & 7)) * 8));
  }

  f32x16 oT00 = {}, oT10 = {}, oT01 = {}, oT11 = {};  // [e-half][q-subtile]
  float l0 = 0.0f, l1 = 0.0f;
  int krow = kb + l32;
  int er0 = l32, er1 = 32 + l32;

  for (int j = 0; j < 32; j++) {
    int cur = j & 1;
    if (j < 31) {   // prefetch tile j+1 into the other buffer
      const bf16* kgn = kg + (size_t)(j + 1) * 64 * 1536;
      const bf16* vgn = vg + (j + 1) * 64;
      char* kbn = smem + 16384 + (cur ^ 1) * 8192 + w * 1024;
      char* vbn = smem + 32768 + (cur ^ 1) * 8192 + w * 1024;
      async16(kbn,        kgn);
      async16(kbn + 4096, kgn + (size_t)32 * 1536);
      async16(vbn,        vgn);
      async16(vbn + 4096, vgn + (size_t)32 * 4096);
    }
    const bf16* Ks = (const bf16*)(smem + 16384 + cur * 8192);
    const bf16* Vs = (const bf16*)(smem + 32768 + cur * 8192);

    // S^T = K Q^T over hd=64 for both q-subtiles (K frags shared)
    f32x16 s0 = {}, s1 = {};
    #pragma unroll
    for (int ks = 0; ks < 4; ks++) {
      bf16x8 kf = *(const bf16x8*)(Ks + krow * 64 + (((ks * 2 + hi) ^ (krow & 7)) * 8));
      s0 = __builtin_amdgcn_mfma_f32_32x32x16_bf16(kf, qf0[ks], s0, 0, 0, 0);
      s1 = __builtin_amdgcn_mfma_f32_32x32x16_bf16(kf, qf1[ks], s1, 0, 0, 0);
    }

    // no-max softmax + in-register P^T fragment build (lane^32 exchange)
    bf16x8 pf00, pf01, pf10, pf11;
    {
      float rs = 0.0f;
      #pragma unroll
      for (int i = 0; i < 16; i++) { float p = fast_exp2(s0[i]); s0[i] = p; rs += p; }
      l0 += rs;
      u32 dd[8], xx[8];
      #pragma unroll
      for (int k = 0; k < 8; k++) dd[k] = pack_bf16(s0[2 * k], s0[2 * k + 1]);
      #pragma unroll
      for (int k = 0; k < 8; k++) xx[k] = __shfl_xor((int)dd[k], 32, 64);
      uint4 a = hi ? uint4{xx[2], xx[3], dd[2], dd[3]} : uint4{dd[0], dd[1], xx[0], xx[1]};
      uint4 b = hi ? uint4{xx[6], xx[7], dd[6], dd[7]} : uint4{dd[4], dd[5], xx[4], xx[5]};
      pf00 = __builtin_bit_cast(bf16x8, a);
      pf01 = __builtin_bit_cast(bf16x8, b);
    }
    {
      float rs = 0.0f;
      #pragma unroll
      for (int i = 0; i < 16; i++) { float p = fast_exp2(s1[i]); s1[i] = p; rs += p; }
      l1 += rs;
      u32 dd[8], xx[8];
      #pragma unroll
      for (int k = 0; k < 8; k++) dd[k] = pack_bf16(s1[2 * k], s1[2 * k + 1]);
      #pragma unroll
      for (int k = 0; k < 8; k++) xx[k] = __shfl_xor((int)dd[k], 32, 64);
      uint4 a = hi ? uint4{xx[2], xx[3], dd[2], dd[3]} : uint4{dd[0], dd[1], xx[0], xx[1]};
      uint4 b = hi ? uint4{xx[6], xx[7], dd[6], dd[7]} : uint4{dd[4], dd[5], xx[4], xx[5]};
      pf10 = __builtin_bit_cast(bf16x8, a);
      pf11 = __builtin_bit_cast(bf16x8, b);
    }

    // O^T += V^T P^T (V frags shared across q-subtiles)
    #pragma unroll
    for (int kstep = 0; kstep < 2; kstep++) {
      int grp = (kb >> 3) + kstep * 2 + hi;
      bf16x8 va = *(const bf16x8*)(Vs + er0 * 64 + ((grp ^ (er0 & 7)) * 8));
      bf16x8 vb = *(const bf16x8*)(Vs + er1 * 64 + ((grp ^ (er1 & 7)) * 8));
      bf16x8 pa = kstep ? pf01 : pf00;
      bf16x8 pb = kstep ? pf11 : pf10;
      oT00 = __builtin_amdgcn_mfma_f32_32x32x16_bf16(va, pa, oT00, 0, 0, 0);
      oT10 = __builtin_amdgcn_mfma_f32_32x32x16_bf16(vb, pa, oT10, 0, 0, 0);
      oT01 = __builtin_amdgcn_mfma_f32_32x32x16_bf16(va, pb, oT01, 0, 0, 0);
      oT11 = __builtin_amdgcn_mfma_f32_32x32x16_bf16(vb, pb, oT11, 0, 0, 0);
    }

    __syncthreads();   // drains j+1 loads (hidden under this iter's compute)
  }

  // cross-ksel combine via LDS; OS stride 67 f32 (coprime 32 -> conflict-free)
  float lq0 = l0 + __shfl_xor(l0, 32, 64);
  float lq1 = l1 + __shfl_xor(l1, 32, 64);
  float* OS = (float*)smem;            // [128 q][67] f32 = 34304 B
  float* LS = (float*)(smem + 34304);  // [128 q] f32
  if (ksel == 1) {
    #pragma unroll
    for (int i = 0; i < 16; i++) {
      int eoff = (i & 3) + 8 * (i >> 2) + 4 * hi;
      OS[qr0 * 67 + eoff]      = oT00[i];
      OS[qr0 * 67 + 32 + eoff] = oT10[i];
      OS[qr1 * 67 + eoff]      = oT01[i];
      OS[qr1 * 67 + 32 + eoff] = oT11[i];
    }
    if (hi == 0) { LS[qr0] = lq0; LS[qr1] = lq1; }
  }
  __syncthreads();
  if (ksel == 0) {
    size_t tb = ((size_t)z * 12 + h) * 32 + qt;
    float la0 = lq0 + LS[qr0], la1 = lq1 + LS[qr1];
    if (hi == 0) { Lpart[tb * 128 + qr0] = la0; Lpart[tb * 128 + qr1] = la1; }
    bf16* ob0 = Opart + tb * 8192 + (size_t)qr0 * 64;
    bf16* ob1 = Opart + tb * 8192 + (size_t)qr1 * 64;
    #pragma unroll
    for (int g = 0; g < 4; g++) {
      int e0 = 8 * g + 4 * hi;
      bf16x4 a0, a1, b0, b1;
      #pragma unroll
      for (int r = 0; r < 4; r++) {
        a0[r] = (bf16)(oT00[g * 4 + r] + OS[qr0 * 67 + e0 + r]);
        a1[r] = (bf16)(oT10[g * 4 + r] + OS[qr0 * 67 + 32 + e0 + r]);
        b0[r] = (bf16)(oT01[g * 4 + r] + OS[qr1 * 67 + e0 + r]);
        b1[r] = (bf16)(oT11[g * 4 + r] + OS[qr1 * 67 + 32 + e0 + r]);
      }
      *(bf16x4*)(ob0 + e0)      = a0;
      *(bf16x4*)(ob0 + 32 + e0) = a1;
      *(bf16x4*)(ob1 + e0)      = b0;
      *(bf16x4*)(ob1 + 32 + e0) = b1;
    }
  }
}

// combine kv-split partials: o = (O0+O1)/(l0+l1); grid (32 qt, 12 h)
__global__ __launch_bounds__(256) void flash_combine_kernel(
    const bf16* __restrict__ Opart, const float* __restrict__ Lpart,
    bf16* __restrict__ o)
{
  int qt = blockIdx.x, h = blockIdx.y;
  int t = threadIdx.x;
  size_t t0 = (size_t)h * 32 + qt;
  size_t t1 = (size_t)(12 + h) * 32 + qt;
  #pragma unroll
  for (int qq = 0; qq < 2; qq++) {
    int q = qq * 64 + (t >> 2), eg = (t & 3) * 16;
    float inv = 1.0f / (Lpart[t0 * 128 + q] + Lpart[t1 * 128 + q]);
    const bf16* p0 = Opart + t0 * 8192 + (size_t)q * 64 + eg;
    const bf16* p1 = Opart + t1 * 8192 + (size_t)q * 64 + eg;
    bf16x8 a0 = *(const bf16x8*)p0, a1 = *(const bf16x8*)(p0 + 8);
    bf16x8 b0 = *(const bf16x8*)p1, b1 = *(const bf16x8*)(p1 + 8);
    bf16x8 r0, r1;
    #pragma unroll
    for (int i = 0; i < 8; i++) {
      r0[i] = (bf16)(((float)a0[i] + (float)b0[i]) * inv);
      r1[i] = (bf16)(((float)a1[i] + (float)b1[i]) * inv);
    }
    bf16* op = o + (size_t)(qt * 128 + q) * 768 + h * 64 + eg;
    *(bf16x8*)op       = r0;
    *(bf16x8*)(op + 8) = r1;
  }
}

extern "C" void kernel_launch(void* const* d_in, const int* in_sizes, int n_in,
                              void* d_out, int out_size, void* d_ws, size_t ws_size,
                              hipStream_t stream) {
  const float* x    = (const float*)d_in[0];
  const float* Wq   = (const float*)d_in[1];
  const float* bq   = (const float*)d_in[2];
  const float* Wk   = (const float*)d_in[3];
  const float* bk   = (const float*)d_in[4];
  const float* Wv   = (const float*)d_in[5];
  const float* bv   = (const float*)d_in[6];
  const float* Wo   = (const float*)d_in[7];
  const float* bo   = (const float*)d_in[8];
  const float* ln1w = (const float*)d_in[9];
  const float* ln1b = (const float*)d_in[10];
  const float* ln2w = (const float*)d_in[11];
  const float* ln2b = (const float*)d_in[12];
  const float* W1   = (const float*)d_in[13];
  const float* b1   = (const float*)d_in[14];
  const float* W2   = (const float*)d_in[15];
  const float* b2   = (const float*)d_in[16];
  float* out = (float*)d_out;

  // workspace layout (58,205,184 B):
  //  0         .. 25165824 : hbuf [4096][3072] bf16 (FFN1 out)
  //                          earlier: Lpart(0..393216) / ybuf(0..6291456, ln1)
  //                          qkbuf(6291456..18874368) / vtg(18874368..25165824)
  //                          opar_o(6291456..12582912, O-proj z=1 partial)
  //  25165824  .. 37748736 : x1 f32 [4096][768]; earlier Opart bf16 [2*12*32][128][64]
  //  37748736  .. 44040192 : obuf/y2buf bf16 [4096][768]; later FFN2 z=1 partial
  //  44040192  .. 58195968 : Wqkv_t | Wo_t | W1_t | W2_t (bf16)
  //  58195968  .. 58205184 : bqkv f32 [2304]
  char* ws = (char*)d_ws;
  bf16*  hbuf   = (bf16*)(ws + 0);
  float* Lpart  = (float*)(ws + 0);
  bf16*  ybuf   = (bf16*)(ws + 0);
  bf16*  qkbuf  = (bf16*)(ws + 6291456);
  bf16*  opar_o = (bf16*)(ws + 6291456);
  bf16*  vtg    = (bf16*)(ws + 18874368);
  float* x1     = (float*)(ws + 25165824);
  bf16*  Opart  = (bf16*)(ws + 25165824);
  bf16*  obuf   = (bf16*)(ws + 37748736);
  bf16*  y2buf  = obuf;
  bf16*  opar_f = obuf;                      // FFN2 z=1 partial (y2 dead)
  bf16*  Wqkv_t = (bf16*)(ws + 44040192);
  bf16*  Wo_t   = (bf16*)(ws + 47579136);
  bf16*  W1_t   = (bf16*)(ws + 48758784);
  bf16*  W2_t   = (bf16*)(ws + 53477376);
  float* bqkv   = (float*)(ws + 58195968);

  // weight prep (ws re-poisoned every call -> reconvert every call)
  conv_qkv_w_kernel<<<dim3(24, 2, 36), 256, 0, stream>>>(Wq, Wk, Wv, Wqkv_t);
  conv_qkv_b_kernel<<<9, 256, 0, stream>>>(bq, bk, bv, bqkv);
  transpose_tile_kernel<<<dim3(24, 24), 256, 0, stream>>>(Wo, Wo_t, 768, 768);
  transpose_tile_kernel<<<dim3(96, 24), 256, 0, stream>>>(W1, W1_t, 768, 3072);
  transpose_tile_kernel<<<dim3(24, 96), 256, 0, stream>>>(W2, W2_t, 3072, 768);

  // 1) y = LN1(x)
  ln_kernel<<<4096, 256, 0, stream>>>(x, ln1w, ln1b, ybuf);
  // 2) qk | v^T = y @ Wqkv + bqkv   (Q pre-scaled by 0.125*log2e)
  gemm_bt<4><<<dim3(18, 32), 256, 0, stream>>>(ybuf, Wqkv_t, bqkv,
                                               (const float*)nullptr, qkbuf, vtg,
                                               4096, 2304, 768);
  // 3) flash attention partials + combine -> obuf [4096][768]
  flash_kernel<<<dim3(32, 12, 2), 256, 0, stream>>>(qkbuf, vtg, Opart, Lpart);
  flash_combine_kernel<<<dim3(32, 12), 256, 0, stream>>>(Opart, Lpart, obuf);
  // 4) x1 = x + obuf @ Wo + bo  (split-K x2, bf16 partial; reduce fused in LN2)
  gemm_bt<5><<<dim3(6, 32, 2), 256, 0, stream>>>(obuf, Wo_t, bo, x, x1, opar_o,
                                                 4096, 768, 768);
  // 5) x1 += opar_o; y2 = LN2(x1)   (fused)
  ln_add_kernel<<<4096, 256, 0, stream>>>(x1, opar_o, ln2w, ln2b, y2buf);
  // 6) h = gelu(y2 @ W1 + b1)
  gemm_bt<2><<<dim3(24, 32), 256, 0, stream>>>(y2buf, W1_t, b1,
                                               (const float*)nullptr, hbuf, nullptr,
                                               4096, 3072, 768);
  // 7) out = x1 + h @ W2 + b2  (split-K x2, bf16 partial + reduce)
  gemm_bt<5><<<dim3(6, 32, 2), 256, 0, stream>>>(hbuf, W2_t, b2, x1, out, opar_f,
                                                 4096, 768, 3072);
  reduce_add_kernel<<<3072, 256, 0, stream>>>(out, opar_f);
}